// Round 12
// baseline (190.461 us; speedup 1.0000x reference)
//
#include <hip/hip_runtime.h>
#include <hip/hip_bf16.h>
#include <math.h>

// ---------------------------------------------------------------------------
// WindowCrossAttention: B=2, S=2048 (32*64), C=256, H=8, Dh=32, HID=1024.
// bf16 MFMA everywhere, fp32 accumulate, fp32 softmax/LN.
// R5: NaN fix. R6: attn main loop proven (42.9 µs). R7-R11: regressions,
// reverted. R12: prep fusion (183.2). R13: merge eliminated (kept).
// R14: global_load_lds staging regressed (reverted). R15: XCD swizzle
// neutral (dropped).
// R16 (this round): SPLIT-K ATTENTION. attn VGPR=60 / LDS=16KB means HW
//   can co-schedule 8 blocks/CU (32 waves, 100%), but grid 1024 = only
//   4/CU -> measured 32% occupancy; kernel is latency-bound with all
//   pipes idle. Split keys across 2 blocks: each covers 1024 keys in 8
//   iters (main loop BYTE-IDENTICAL per iteration), grid 2048 = 8/CU.
//   Blocks write unnormalized partial O (f32) + partial L; new tiny
//   attn_reduce kernel (~3.5 µs) combines halves -> bf16 acat.
// ---------------------------------------------------------------------------

typedef float  f32x4  __attribute__((ext_vector_type(4)));
typedef __bf16 bf16x8 __attribute__((ext_vector_type(8)));

#define MFMA16(A, B, C) __builtin_amdgcn_mfma_f32_16x16x32_bf16((A), (B), (C), 0, 0, 0)

static constexpr int   ROWS  = 8192;       // 2 tensors * B(2) * S(2048)
// 32^-0.25 * sqrt(log2(e)) — folds exp->exp2 conversion into the projection
static constexpr float QK_SCALE = 0.42044820762685725f * 1.2011224087864498f;

__device__ inline unsigned short f2b(float f) {
    __hip_bfloat16 h = __float2bfloat16(f);
    union { __hip_bfloat16 h; unsigned short u; } cv;
    cv.h = h;
    return cv.u;
}

__device__ inline float exp2_fast(float x) {
#if __has_builtin(__builtin_amdgcn_exp2f)
    return __builtin_amdgcn_exp2f(x);
#else
    return __exp2f(x);
#endif
}

__device__ inline float gelu_f(float x) {
    // tanh-form GELU via exp; |err vs exact erf-GELU| < ~3e-3, absorbed by LN2.
    float z = 0.7978845608028654f * (x + 0.044715f * x * x * x);
    z = fminf(fmaxf(z, -15.0f), 15.0f);
    const float e = __expf(-2.0f * z);
    const float t = (1.0f - e) / (1.0f + e);
    return 0.5f * x * (1.0f + t);
}

// -------- fused prep: weight cvt + LN1 + W1eff = W1b@Wm (3 block ranges) ----
// Weight region layout (ushort): [0,131072) wqv ; [131072,655360) w1f
// ([1024,512]: cols 0-255 = W1a cvt, cols 256-511 = W1eff GEMM) ;
// [655360,917504) w2.
// Blocks 0..2559    : cvt wq, wv, W1a, w2 (655360 elems)
// Blocks 2560..4607 : LN1 (4 rows/block) + bf16(x) into acat cols 0-255
// Blocks 4608..4671 : W1eff 64x64 tiles (K=256), fp32 inputs staged to bf16
__global__ __launch_bounds__(256) void prep_kernel(
    const float* __restrict__ qkw, const float* __restrict__ vw,
    const float* __restrict__ mw,  const float* __restrict__ w1,
    const float* __restrict__ w2,  unsigned short* __restrict__ o,
    const float* __restrict__ x0,  const float* __restrict__ x1,
    const float* __restrict__ lw,  const float* __restrict__ lb,
    unsigned short* __restrict__ nb, unsigned short* __restrict__ acat)
{
    __shared__ unsigned short As[64 * 72];
    __shared__ unsigned short Ws[64 * 72];
    if (blockIdx.x < 2560) {
        int i = blockIdx.x * 256 + threadIdx.x;
        if      (i <  65536) o[i] = f2b(qkw[i]);
        else if (i < 131072) o[i] = f2b(vw[i - 65536]);
        else if (i < 393216) {
            int j = i - 131072, r = j >> 8, c = j & 255;
            o[131072 + r * 512 + c] = f2b(w1[(size_t)r * 512 + c]);   // W1a
        } else {
            o[i + 262144] = f2b(w2[i - 393216]);                      // w2
        }
        return;
    }
    if (blockIdx.x < 4608) {   // ---- LN1 ----
        const int wid  = threadIdx.x >> 6;
        const int lane = threadIdx.x & 63;
        const int row  = (blockIdx.x - 2560) * 4 + wid;
        const float* xr = (row < 4096) ? (x0 + (size_t)row * 256)
                                       : (x1 + (size_t)(row - 4096) * 256);
        const int c0 = lane * 4;
        const float4 xv = *(const float4*)(xr + c0);
        float s  = (xv.x + xv.y) + (xv.z + xv.w);
        float sq = (xv.x * xv.x + xv.y * xv.y) + (xv.z * xv.z + xv.w * xv.w);
#pragma unroll
        for (int off = 1; off < 64; off <<= 1) {
            s  += __shfl_xor(s,  off);
            sq += __shfl_xor(sq, off);
        }
        const float mean = s * (1.0f / 256.0f);
        const float var  = sq * (1.0f / 256.0f) - mean * mean;
        const float rs   = rsqrtf(var + 1e-5f);
        const float4 wv4 = *(const float4*)(lw + c0);
        const float4 bv4 = *(const float4*)(lb + c0);
        ushort4 nv;
        nv.x = f2b((xv.x - mean) * rs * wv4.x + bv4.x);
        nv.y = f2b((xv.y - mean) * rs * wv4.y + bv4.y);
        nv.z = f2b((xv.z - mean) * rs * wv4.z + bv4.z);
        nv.w = f2b((xv.w - mean) * rs * wv4.w + bv4.w);
        *(ushort4*)(nb + (size_t)row * 256 + c0) = nv;
        ushort4 xb;
        xb.x = f2b(xv.x); xb.y = f2b(xv.y); xb.z = f2b(xv.z); xb.w = f2b(xv.w);
        *(ushort4*)(acat + (size_t)row * 512 + c0) = xb;
        return;
    }
    // ---- W1eff[i,j] = sum_k W1[i, 256+k] * Wm[k, j]  (64x64 tile) ----
    const int t   = blockIdx.x - 4608;
    const int i0  = (t >> 2) * 64;
    const int j0  = (t & 3) * 64;
    const int tid  = threadIdx.x;
    const int wid  = tid >> 6;
    const int lane = tid & 63;
    const int ln   = lane & 15;
    const int quad = lane >> 4;
    f32x4 acc[4] = {{0,0,0,0},{0,0,0,0},{0,0,0,0},{0,0,0,0}};
    const int srow = tid >> 3;          // 0..31 (and +32)
    const int skc  = (tid & 7) * 8;
    for (int k0 = 0; k0 < 256; k0 += 64) {
#pragma unroll
        for (int rr = 0; rr < 2; ++rr) {
            const int row = srow + rr * 32;
            // A: W1b row (fp32 -> bf16)
            const float* asrc = w1 + (size_t)(i0 + row) * 512 + 256 + k0 + skc;
            const float4 f0 = *(const float4*)(asrc);
            const float4 f1 = *(const float4*)(asrc + 4);
            ushort4 a0, a1;
            a0.x = f2b(f0.x); a0.y = f2b(f0.y); a0.z = f2b(f0.z); a0.w = f2b(f0.w);
            a1.x = f2b(f1.x); a1.y = f2b(f1.y); a1.z = f2b(f1.z); a1.w = f2b(f1.w);
            *(ushort4*)(As + row * 72 + skc)     = a0;
            *(ushort4*)(As + row * 72 + skc + 4) = a1;
            // B: Ws[j][k] = Wm[k, j]  (strided fp32 -> bf16; tiny matrix)
            const float* bsrc = mw + (size_t)(k0 + skc) * 256 + (j0 + row);
            ushort4 b0, b1;
            b0.x = f2b(bsrc[0 * 256]); b0.y = f2b(bsrc[1 * 256]);
            b0.z = f2b(bsrc[2 * 256]); b0.w = f2b(bsrc[3 * 256]);
            b1.x = f2b(bsrc[4 * 256]); b1.y = f2b(bsrc[5 * 256]);
            b1.z = f2b(bsrc[6 * 256]); b1.w = f2b(bsrc[7 * 256]);
            *(ushort4*)(Ws + row * 72 + skc)     = b0;
            *(ushort4*)(Ws + row * 72 + skc + 4) = b1;
        }
        __syncthreads();
#pragma unroll
        for (int kk = 0; kk < 64; kk += 32) {
            const bf16x8 af = *(const bf16x8*)(As + (wid * 16 + ln) * 72 + kk + quad * 8);
#pragma unroll
            for (int f = 0; f < 4; ++f) {
                const bf16x8 wf = *(const bf16x8*)(Ws + (f * 16 + ln) * 72 + kk + quad * 8);
                acc[f] = MFMA16(wf, af, acc[f]);
            }
        }
        __syncthreads();
    }
    const int rowm = i0 + wid * 16 + ln;
#pragma unroll
    for (int f = 0; f < 4; ++f) {
        const int cb = j0 + f * 16 + quad * 4;
        ushort4 ov;
        ov.x = f2b(acc[f][0]); ov.y = f2b(acc[f][1]);
        ov.z = f2b(acc[f][2]); ov.w = f2b(acc[f][3]);
        *(ushort4*)(o + 131072 + (size_t)rowm * 512 + 256 + cb) = ov;
    }
}

// --------------------- fused qk+v projection (64x64 tile) -------------------
// A[8192,256] @ Wqv[512,256]^T. Cols 0-255 -> qkb (scaled, row-major).
// Cols 256-511 -> vtb TRANSPOSED: vtb[feat*8192 + token].
__global__ __launch_bounds__(256) void gemm_qkv(
    const unsigned short* __restrict__ A, const unsigned short* __restrict__ W,
    unsigned short* __restrict__ qkb, unsigned short* __restrict__ vtb)
{
    constexpr int K = 256;
    __shared__ unsigned short As[64 * 72];
    __shared__ unsigned short Ws[64 * 72];
    const int tid  = threadIdx.x;
    const int wid  = tid >> 6;
    const int lane = tid & 63;
    const int ln   = lane & 15;
    const int quad = lane >> 4;
    const int m0 = blockIdx.x * 64, n0 = blockIdx.y * 64;
    f32x4 acc[4] = {{0,0,0,0},{0,0,0,0},{0,0,0,0},{0,0,0,0}};
    const int srow = tid >> 3;          // 0..31 (and +32)
    const int skc  = (tid & 7) * 8;
    const unsigned short* aP0 = A + (size_t)(m0 + srow)      * K + skc;
    const unsigned short* aP1 = A + (size_t)(m0 + srow + 32) * K + skc;
    const unsigned short* wP0 = W + (size_t)(n0 + srow)      * K + skc;
    const unsigned short* wP1 = W + (size_t)(n0 + srow + 32) * K + skc;
    for (int k0 = 0; k0 < K; k0 += 64) {
        *(uint4*)(As + srow * 72 + skc)        = *(const uint4*)(aP0 + k0);
        *(uint4*)(As + (srow + 32) * 72 + skc) = *(const uint4*)(aP1 + k0);
        *(uint4*)(Ws + srow * 72 + skc)        = *(const uint4*)(wP0 + k0);
        *(uint4*)(Ws + (srow + 32) * 72 + skc) = *(const uint4*)(wP1 + k0);
        __syncthreads();
#pragma unroll
        for (int kk = 0; kk < 64; kk += 32) {
            const bf16x8 af = *(const bf16x8*)(As + (wid * 16 + ln) * 72 + kk + quad * 8);
#pragma unroll
            for (int f = 0; f < 4; ++f) {
                const bf16x8 wf = *(const bf16x8*)(Ws + (f * 16 + ln) * 72 + kk + quad * 8);
                acc[f] = MFMA16(wf, af, acc[f]);
            }
        }
        __syncthreads();
    }
    const int rowm = m0 + wid * 16 + ln;
    if (n0 < 256) {   // qk half, scaled, row-major
#pragma unroll
        for (int f = 0; f < 4; ++f) {
            const int cb = n0 + f * 16 + quad * 4;
            ushort4 o;
            o.x = f2b(acc[f][0] * QK_SCALE); o.y = f2b(acc[f][1] * QK_SCALE);
            o.z = f2b(acc[f][2] * QK_SCALE); o.w = f2b(acc[f][3] * QK_SCALE);
            *(ushort4*)(qkb + (size_t)rowm * 256 + cb) = o;
        }
    } else {          // v half, transposed store [feat][token]
#pragma unroll
        for (int f = 0; f < 4; ++f) {
            const int cb = (n0 - 256) + f * 16 + quad * 4;
#pragma unroll
            for (int r = 0; r < 4; ++r)
                vtb[(size_t)(cb + r) * 8192 + rowm] = f2b(acc[f][r]);
        }
    }
}

// ------------------------- 128x128-tile GEMM (fc1/fc2) ----------------------
// 4 waves, each 64x64 (4x4 frags). out = act(A@W^T + bias).
// R12-proven staging: uint4 -> padded-72 LDS.
template <bool GELU_, bool OUTB>
__global__ __launch_bounds__(256) void gemm128(
    const unsigned short* __restrict__ A, const unsigned short* __restrict__ W,
    const float* __restrict__ bias,
    unsigned short* __restrict__ outB, float* __restrict__ outF,
    int K, int NS)   // NS = output row stride
{
    __shared__ unsigned short As[128 * 72];
    __shared__ unsigned short Ws[128 * 72];
    const int tid  = threadIdx.x;
    const int wid  = tid >> 6;
    const int lane = tid & 63;
    const int ln   = lane & 15;
    const int quad = lane >> 4;
    const int m0 = blockIdx.x * 128, n0 = blockIdx.y * 128;
    const int wm = (wid & 1) * 64, wn = (wid >> 1) * 64;
    f32x4 acc[4][4];
#pragma unroll
    for (int f = 0; f < 4; ++f)
#pragma unroll
        for (int i = 0; i < 4; ++i) acc[f][i] = (f32x4){0, 0, 0, 0};
    const int sr = tid >> 2;        // 0..63 (and +64)
    const int sc = (tid & 3) * 8;   // 0..24 (and +32)
    for (int k0 = 0; k0 < K; k0 += 64) {
        const unsigned short* aB = A + (size_t)m0 * K + k0;
        const unsigned short* wB = W + (size_t)n0 * K + k0;
        *(uint4*)(As + sr * 72 + sc)             = *(const uint4*)(aB + (size_t)sr * K + sc);
        *(uint4*)(As + sr * 72 + sc + 32)        = *(const uint4*)(aB + (size_t)sr * K + sc + 32);
        *(uint4*)(As + (sr + 64) * 72 + sc)      = *(const uint4*)(aB + (size_t)(sr + 64) * K + sc);
        *(uint4*)(As + (sr + 64) * 72 + sc + 32) = *(const uint4*)(aB + (size_t)(sr + 64) * K + sc + 32);
        *(uint4*)(Ws + sr * 72 + sc)             = *(const uint4*)(wB + (size_t)sr * K + sc);
        *(uint4*)(Ws + sr * 72 + sc + 32)        = *(const uint4*)(wB + (size_t)sr * K + sc + 32);
        *(uint4*)(Ws + (sr + 64) * 72 + sc)      = *(const uint4*)(wB + (size_t)(sr + 64) * K + sc);
        *(uint4*)(Ws + (sr + 64) * 72 + sc + 32) = *(const uint4*)(wB + (size_t)(sr + 64) * K + sc + 32);
        __syncthreads();
#pragma unroll
        for (int kk = 0; kk < 64; kk += 32) {
            bf16x8 af[4], wf[4];
#pragma unroll
            for (int i = 0; i < 4; ++i)
                af[i] = *(const bf16x8*)(As + (wm + i * 16 + ln) * 72 + kk + quad * 8);
#pragma unroll
            for (int f = 0; f < 4; ++f)
                wf[f] = *(const bf16x8*)(Ws + (wn + f * 16 + ln) * 72 + kk + quad * 8);
#pragma unroll
            for (int f = 0; f < 4; ++f)
#pragma unroll
                for (int i = 0; i < 4; ++i)
                    acc[f][i] = MFMA16(wf[f], af[i], acc[f][i]);
        }
        __syncthreads();
    }
#pragma unroll
    for (int f = 0; f < 4; ++f) {
        const int feat = n0 + wn + f * 16 + quad * 4;
        const float4 b4 = *(const float4*)(bias + feat);
#pragma unroll
        for (int i = 0; i < 4; ++i) {
            const int token = m0 + wm + i * 16 + ln;
            float vv[4] = {acc[f][i][0] + b4.x, acc[f][i][1] + b4.y,
                           acc[f][i][2] + b4.z, acc[f][i][3] + b4.w};
            if (GELU_) {
#pragma unroll
                for (int r = 0; r < 4; ++r) vv[r] = gelu_f(vv[r]);
            }
            if (OUTB) {
                ushort4 o;
                o.x = f2b(vv[0]); o.y = f2b(vv[1]); o.z = f2b(vv[2]); o.w = f2b(vv[3]);
                *(ushort4*)(outB + (size_t)token * NS + feat) = o;
            } else {
                float4 o = {vv[0], vv[1], vv[2], vv[3]};
                *(float4*)(outF + (size_t)token * NS + feat) = o;
            }
        }
    }
}

// ------------------------------- Attention ---------------------------------
// dir 0: m0 = softmax_s(sim) @ v1 ; dir 1: m1 = softmax_l(sim)^T @ v0.
// R16 split-K: grid (32,16,4), z = dir*2 + half. Each block covers 1024
// keys (8 iters, main loop per-iteration BYTE-IDENTICAL to R6). Epilogue
// writes unnormalized partial O (f32) + partial L per (row, h) to
// workspace; attn_reduce combines the two halves.
__global__ __launch_bounds__(256, 4) void attn_kernel(
    const unsigned short* __restrict__ qk, const unsigned short* __restrict__ vtb,
    float* __restrict__ pO, float* __restrict__ pL)
{
    __shared__ unsigned short Pw[4][64 * 32];  // per-wave P [64 q][32 keys], swizzled
    const int tid  = threadIdx.x;
    const int wid  = tid >> 6;
    const int lane = tid & 63;
    const int ln   = lane & 15;
    const int quad = lane >> 4;
    const int half = blockIdx.z & 1, dir = blockIdx.z >> 1;
    const int bh = blockIdx.y;
    const int b = bh >> 3, h = bh & 7;
    const int qbase = b * 2048 + (dir ? 4096 : 0);
    const int kbase = b * 2048 + (dir ? 0 : 4096) + half * 1024;
    const int q0 = blockIdx.x * 64;
    const int xsw = ((ln >> 1) & 1) << 4;   // xor swizzle, 16-ushort granule

    // Q fragments (B-operand): lane -> q row = ln, d-chunk = quad.
    bf16x8 qf[4];
#pragma unroll
    for (int qg = 0; qg < 4; ++qg)
        qf[qg] = *(const bf16x8*)(qk + (size_t)(qbase + q0 + qg * 16 + ln) * 256 + h * 32 + quad * 8);

    f32x4 oacc[4][2];
#pragma unroll
    for (int qg = 0; qg < 4; ++qg) {
        oacc[qg][0] = (f32x4){0, 0, 0, 0};
        oacc[qg][1] = (f32x4){0, 0, 0, 0};
    }
    float lp[4] = {0.0f, 0.0f, 0.0f, 0.0f};
    const f32x4 zf = {0, 0, 0, 0};

    // this wave's key slice: keys kbase + it*128 + wid*32 + [0..32), it<8
    const unsigned short* kp = qk  + (size_t)(kbase + wid * 32 + ln) * 256 + h * 32 + quad * 8;
    const unsigned short* vp = vtb + (size_t)(h * 32 + ln) * 8192 + (kbase + wid * 32) + quad * 8;

    unsigned short* Pq[4];
#pragma unroll
    for (int qg = 0; qg < 4; ++qg) Pq[qg] = &Pw[wid][(qg * 16 + ln) * 32];

    bf16x8 kc0 = *(const bf16x8*)(kp);
    bf16x8 kc1 = *(const bf16x8*)(kp + 16 * 256);
    bf16x8 vc0 = *(const bf16x8*)(vp);
    bf16x8 vc1 = *(const bf16x8*)(vp + 16 * 8192);
    bf16x8 kn0, kn1, vn0, vn1;

    for (int it = 0; it < 8; ++it) {
        // S^T = K @ Q^T for the 32-key slice (C: row=key, col=q) -> exp -> P
#pragma unroll
        for (int sub = 0; sub < 2; ++sub) {
            const bf16x8 kf = sub ? kc1 : kc0;
            f32x4 s[4];
#pragma unroll
            for (int qg = 0; qg < 4; ++qg) s[qg] = MFMA16(kf, qf[qg], zf);
#pragma unroll
            for (int qg = 0; qg < 4; ++qg) {
                const float e0 = exp2_fast(s[qg][0]), e1 = exp2_fast(s[qg][1]);
                const float e2 = exp2_fast(s[qg][2]), e3 = exp2_fast(s[qg][3]);
                lp[qg] += (e0 + e1) + (e2 + e3);
                ushort4 pb;
                pb.x = f2b(e0); pb.y = f2b(e1); pb.z = f2b(e2); pb.w = f2b(e3);
                // P[q][key = sub*16 + quad*4 + r], chunk xor-swizzled
                *(ushort4*)(Pq[qg] + ((sub * 16 + quad * 4) ^ xsw)) = pb;
            }
        }
        // prefetch next key slice (global; vmcnt-tracked, unaffected by lgkm fence)
        if (it < 7) {
            const unsigned short* kpn = kp + (size_t)(it + 1) * 128 * 256;
            const unsigned short* vpn = vp + (it + 1) * 128;
            kn0 = *(const bf16x8*)(kpn);
            kn1 = *(const bf16x8*)(kpn + 16 * 256);
            vn0 = *(const bf16x8*)(vpn);
            vn1 = *(const bf16x8*)(vpn + 16 * 8192);
        }
        // P is wave-private: drain own ds_writes before reading (no barrier)
        asm volatile("s_waitcnt lgkmcnt(0)" ::: "memory");
        // O^T += V^T @ P  (k = 32 keys, exactly this wave's slice)
#pragma unroll
        for (int qg = 0; qg < 4; ++qg) {
            const bf16x8 pf = *(const bf16x8*)(Pq[qg] + ((quad * 8) ^ xsw));
            oacc[qg][0] = MFMA16(vc0, pf, oacc[qg][0]);
            oacc[qg][1] = MFMA16(vc1, pf, oacc[qg][1]);
        }
        if (it < 7) { kc0 = kn0; kc1 = kn1; vc0 = vn0; vc1 = vn1; }
    }

    // ---- cross-wave reduction, then store PARTIALS (split-K) ----
#pragma unroll
    for (int qg = 0; qg < 4; ++qg) {   // sum over quads -> full wave-slice sum
        lp[qg] += __shfl_xor(lp[qg], 16);
        lp[qg] += __shfl_xor(lp[qg], 32);
    }
    __syncthreads();                   // all waves done with their Pw
    float* scr  = (float*)&Pw[0][0];
    float* Lbuf = scr;                 // [4 wid][64 q]
    float* Obuf = scr + 256;           // [4 wid][2 dg][64 lane][4]
    if (quad == 0) {
#pragma unroll
        for (int qg = 0; qg < 4; ++qg) Lbuf[wid * 64 + qg * 16 + ln] = lp[qg];
    }
#pragma unroll
    for (int qg = 0; qg < 4; ++qg) {
#pragma unroll
        for (int dg = 0; dg < 2; ++dg)
            *(f32x4*)&Obuf[(wid * 2 + dg) * 256 + lane * 4] = oacc[qg][dg];
        __syncthreads();
        if (wid == qg) {
            const int q = qg * 16 + ln;
            const int row = qbase + q0 + q;
            if (quad == 0)
                pL[(size_t)half * ROWS * 8 + (size_t)row * 8 + h] =
                    Lbuf[q] + Lbuf[64 + q] + Lbuf[128 + q] + Lbuf[192 + q];
#pragma unroll
            for (int dg = 0; dg < 2; ++dg) {
                f32x4 sum = *(f32x4*)&Obuf[(0 + dg) * 256 + lane * 4];
#pragma unroll
                for (int w = 1; w < 4; ++w)
                    sum += *(f32x4*)&Obuf[(w * 2 + dg) * 256 + lane * 4];
                *(f32x4*)(pO + ((size_t)half * ROWS + row) * 256
                             + h * 32 + dg * 16 + quad * 4) = sum;
            }
        }
        __syncthreads();
    }
}

// ---------------- split-K combine: (O0+O1)/(L0+L1) -> bf16 acat -------------
__global__ __launch_bounds__(256) void attn_reduce(
    const float* __restrict__ pO, const float* __restrict__ pL,
    unsigned short* __restrict__ acat)
{
    const int row = blockIdx.x * 4 + (threadIdx.x >> 6);
    const int c0  = (threadIdx.x & 63) * 4;
    const int h   = c0 >> 5;
    const f32x4 o0 = *(const f32x4*)(pO + (size_t)row * 256 + c0);
    const f32x4 o1 = *(const f32x4*)(pO + ((size_t)ROWS + row) * 256 + c0);
    const float L  = pL[(size_t)row * 8 + h] + pL[(size_t)ROWS * 8 + (size_t)row * 8 + h];
    const float rinv = 1.0f / L;
    ushort4 o;
    o.x = f2b((o0[0] + o1[0]) * rinv); o.y = f2b((o0[1] + o1[1]) * rinv);
    o.z = f2b((o0[2] + o1[2]) * rinv); o.w = f2b((o0[3] + o1[3]) * rinv);
    *(ushort4*)(acat + (size_t)row * 512 + 256 + c0) = o;
}

// ------------------------ residual + gamma * LN2(h) -------------------------
__global__ __launch_bounds__(256) void ln_out_kernel(
    const float* __restrict__ x0, const float* __restrict__ x1,
    const float* __restrict__ h2, const float* __restrict__ w,
    const float* __restrict__ b,  const float* __restrict__ gamma,
    float* __restrict__ out)
{
    const int wid  = threadIdx.x >> 6;
    const int lane = threadIdx.x & 63;
    const int row  = blockIdx.x * 4 + wid;
    const int c0 = lane * 4;
    const float4 hv = *(const float4*)(h2 + (size_t)row * 256 + c0);
    float s  = (hv.x + hv.y) + (hv.z + hv.w);
    float sq = (hv.x * hv.x + hv.y * hv.y) + (hv.z * hv.z + hv.w * hv.w);
#pragma unroll
    for (int off = 1; off < 64; off <<= 1) {
        s  += __shfl_xor(s,  off);
        sq += __shfl_xor(sq, off);
    }
    const float mean = s * (1.0f / 256.0f);
    const float var  = sq * (1.0f / 256.0f) - mean * mean;
    const float rs   = rsqrtf(var + 1e-5f);
    const float* xr = (row < 4096) ? (x0 + (size_t)row * 256)
                                   : (x1 + (size_t)(row - 4096) * 256);
    const float4 xv = *(const float4*)(xr + c0);
    const float4 w4 = *(const float4*)(w + c0);
    const float4 b4 = *(const float4*)(b + c0);
    const float4 g4 = *(const float4*)(gamma + c0);
    float4 y;
    y.x = xv.x + g4.x * ((hv.x - mean) * rs * w4.x + b4.x);
    y.y = xv.y + g4.y * ((hv.y - mean) * rs * w4.y + b4.y);
    y.z = xv.z + g4.z * ((hv.z - mean) * rs * w4.z + b4.z);
    y.w = xv.w + g4.w * ((hv.w - mean) * rs * w4.w + b4.w);
    *(float4*)(out + (size_t)row * 256 + c0) = y;
}

// ---------------------------------------------------------------------------
extern "C" void kernel_launch(void* const* d_in, const int* in_sizes, int n_in,
                              void* d_out, int out_size, void* d_ws, size_t ws_size,
                              hipStream_t stream) {
    (void)in_sizes; (void)n_in; (void)out_size; (void)ws_size;
    const float* x0      = (const float*)d_in[0];
    const float* x1      = (const float*)d_in[1];
    const float* qk_w    = (const float*)d_in[2];
    const float* v_w     = (const float*)d_in[3];
    const float* merge_w = (const float*)d_in[4];
    const float* ln1_w   = (const float*)d_in[5];
    const float* ln1_b   = (const float*)d_in[6];
    const float* ln2_w   = (const float*)d_in[7];
    const float* ln2_b   = (const float*)d_in[8];
    const float* fc1_w   = (const float*)d_in[9];
    const float* fc1_b   = (const float*)d_in[10];
    const float* fc2_w   = (const float*)d_in[11];
    const float* fc2_b   = (const float*)d_in[12];
    const float* gamma   = (const float*)d_in[13];
    float* out = (float*)d_out;

    unsigned short* nb   = (unsigned short*)d_ws;            // [8192,256] LN1 out
    unsigned short* qkb  = nb   + (size_t)ROWS * 256;        // [8192,256] qk proj (scaled)
    unsigned short* vtb  = qkb  + (size_t)ROWS * 256;        // [256,8192] v proj TRANSPOSED
    unsigned short* acat = vtb  + (size_t)ROWS * 256;        // [8192,512] concat(x, attn)
    unsigned short* fc1o = acat + (size_t)ROWS * 512;        // [8192,1024] gelu(fc1)
    float*          h2   = (float*)(fc1o + (size_t)ROWS * 1024);  // [8192,256] fc2 out
    unsigned short* wqv  = (unsigned short*)(h2 + (size_t)ROWS * 256);  // [512,256]
    unsigned short* w1f  = wqv + 131072;                     // [1024,512] fused fc1 W
    unsigned short* w2b  = w1f + 524288;                     // [256,1024]
    float*          pO   = (float*)(w2b + 262144);           // [2][8192][256] f32
    float*          pL   = pO + (size_t)2 * ROWS * 256;      // [2][8192][8]  f32

    prep_kernel<<<4672, 256, 0, stream>>>(
        qk_w, v_w, merge_w, fc1_w, fc2_w, wqv,
        x0, x1, ln1_w, ln1_b, nb, acat);

    gemm_qkv<<<dim3(128, 8), 256, 0, stream>>>(nb, wqv, qkb, vtb);

    attn_kernel<<<dim3(32, 16, 4), 256, 0, stream>>>(qkb, vtb, pO, pL);
    attn_reduce<<<2048, 256, 0, stream>>>(pO, pL, acat);

    gemm128<true, true><<<dim3(64, 8), 256, 0, stream>>>(
        acat, w1f, fc1_b, fc1o, nullptr, 512, 1024);
    gemm128<false, false><<<dim3(64, 2), 256, 0, stream>>>(
        fc1o, w2b, fc2_b, nullptr, h2, 1024, 256);

    ln_out_kernel<<<2048, 256, 0, stream>>>(x0, x1, h2, ln2_w, ln2_b, gamma, out);
}

// Round 13
// 182.900 us; speedup vs baseline: 1.0413x; 1.0413x over previous
//
#include <hip/hip_runtime.h>
#include <hip/hip_bf16.h>
#include <math.h>

// ---------------------------------------------------------------------------
// WindowCrossAttention: B=2, S=2048 (32*64), C=256, H=8, Dh=32, HID=1024.
// bf16 MFMA everywhere, fp32 accumulate, fp32 softmax/LN.
// R5: NaN fix (exp2 builtin). R6: attn main loop proven (42.9 µs).
// R7-R11: five attn/GEMM restructurings regressed; reverted.
// R12: prep fusion (183.2). R13: algebraic merge elimination (kept).
// R14: global_load_lds staging regressed (reverted). R15: XCD swizzle
// neutral (dropped). R16: split-K attn — occupancy did NOT rise with 2x
// grid (hard ~4 blocks/CU cap), +16MB partial traffic, 44.2 µs. REVERTED.
// R17 (this round): bank the best measured configuration (= R13 form).
// Latency-bound attn theory falsified 3 ways (regs/grid/prefetch); all
// configs in the 183-185 band are statistically tied; everything else
// measured worse. This is the plateau form of this decomposition family.
// ---------------------------------------------------------------------------

typedef float  f32x4  __attribute__((ext_vector_type(4)));
typedef __bf16 bf16x8 __attribute__((ext_vector_type(8)));

#define MFMA16(A, B, C) __builtin_amdgcn_mfma_f32_16x16x32_bf16((A), (B), (C), 0, 0, 0)

static constexpr int   ROWS  = 8192;       // 2 tensors * B(2) * S(2048)
// 32^-0.25 * sqrt(log2(e)) — folds exp->exp2 conversion into the projection
static constexpr float QK_SCALE = 0.42044820762685725f * 1.2011224087864498f;

__device__ inline unsigned short f2b(float f) {
    __hip_bfloat16 h = __float2bfloat16(f);
    union { __hip_bfloat16 h; unsigned short u; } cv;
    cv.h = h;
    return cv.u;
}

__device__ inline float exp2_fast(float x) {
#if __has_builtin(__builtin_amdgcn_exp2f)
    return __builtin_amdgcn_exp2f(x);
#else
    return __exp2f(x);
#endif
}

__device__ inline float gelu_f(float x) {
    // tanh-form GELU via exp; |err vs exact erf-GELU| < ~3e-3, absorbed by LN2.
    float z = 0.7978845608028654f * (x + 0.044715f * x * x * x);
    z = fminf(fmaxf(z, -15.0f), 15.0f);
    const float e = __expf(-2.0f * z);
    const float t = (1.0f - e) / (1.0f + e);
    return 0.5f * x * (1.0f + t);
}

// -------- fused prep: weight cvt + LN1 + W1eff = W1b@Wm (3 block ranges) ----
// Weight region layout (ushort): [0,131072) wqv ; [131072,655360) w1f
// ([1024,512]: cols 0-255 = W1a cvt, cols 256-511 = W1eff GEMM) ;
// [655360,917504) w2.
// Blocks 0..2559    : cvt wq, wv, W1a, w2 (655360 elems)
// Blocks 2560..4607 : LN1 (4 rows/block) + bf16(x) into acat cols 0-255
// Blocks 4608..4671 : W1eff 64x64 tiles (K=256), fp32 inputs staged to bf16
__global__ __launch_bounds__(256) void prep_kernel(
    const float* __restrict__ qkw, const float* __restrict__ vw,
    const float* __restrict__ mw,  const float* __restrict__ w1,
    const float* __restrict__ w2,  unsigned short* __restrict__ o,
    const float* __restrict__ x0,  const float* __restrict__ x1,
    const float* __restrict__ lw,  const float* __restrict__ lb,
    unsigned short* __restrict__ nb, unsigned short* __restrict__ acat)
{
    __shared__ unsigned short As[64 * 72];
    __shared__ unsigned short Ws[64 * 72];
    if (blockIdx.x < 2560) {
        int i = blockIdx.x * 256 + threadIdx.x;
        if      (i <  65536) o[i] = f2b(qkw[i]);
        else if (i < 131072) o[i] = f2b(vw[i - 65536]);
        else if (i < 393216) {
            int j = i - 131072, r = j >> 8, c = j & 255;
            o[131072 + r * 512 + c] = f2b(w1[(size_t)r * 512 + c]);   // W1a
        } else {
            o[i + 262144] = f2b(w2[i - 393216]);                      // w2
        }
        return;
    }
    if (blockIdx.x < 4608) {   // ---- LN1 ----
        const int wid  = threadIdx.x >> 6;
        const int lane = threadIdx.x & 63;
        const int row  = (blockIdx.x - 2560) * 4 + wid;
        const float* xr = (row < 4096) ? (x0 + (size_t)row * 256)
                                       : (x1 + (size_t)(row - 4096) * 256);
        const int c0 = lane * 4;
        const float4 xv = *(const float4*)(xr + c0);
        float s  = (xv.x + xv.y) + (xv.z + xv.w);
        float sq = (xv.x * xv.x + xv.y * xv.y) + (xv.z * xv.z + xv.w * xv.w);
#pragma unroll
        for (int off = 1; off < 64; off <<= 1) {
            s  += __shfl_xor(s,  off);
            sq += __shfl_xor(sq, off);
        }
        const float mean = s * (1.0f / 256.0f);
        const float var  = sq * (1.0f / 256.0f) - mean * mean;
        const float rs   = rsqrtf(var + 1e-5f);
        const float4 wv4 = *(const float4*)(lw + c0);
        const float4 bv4 = *(const float4*)(lb + c0);
        ushort4 nv;
        nv.x = f2b((xv.x - mean) * rs * wv4.x + bv4.x);
        nv.y = f2b((xv.y - mean) * rs * wv4.y + bv4.y);
        nv.z = f2b((xv.z - mean) * rs * wv4.z + bv4.z);
        nv.w = f2b((xv.w - mean) * rs * wv4.w + bv4.w);
        *(ushort4*)(nb + (size_t)row * 256 + c0) = nv;
        ushort4 xb;
        xb.x = f2b(xv.x); xb.y = f2b(xv.y); xb.z = f2b(xv.z); xb.w = f2b(xv.w);
        *(ushort4*)(acat + (size_t)row * 512 + c0) = xb;
        return;
    }
    // ---- W1eff[i,j] = sum_k W1[i, 256+k] * Wm[k, j]  (64x64 tile) ----
    const int t   = blockIdx.x - 4608;
    const int i0  = (t >> 2) * 64;
    const int j0  = (t & 3) * 64;
    const int tid  = threadIdx.x;
    const int wid  = tid >> 6;
    const int lane = tid & 63;
    const int ln   = lane & 15;
    const int quad = lane >> 4;
    f32x4 acc[4] = {{0,0,0,0},{0,0,0,0},{0,0,0,0},{0,0,0,0}};
    const int srow = tid >> 3;          // 0..31 (and +32)
    const int skc  = (tid & 7) * 8;
    for (int k0 = 0; k0 < 256; k0 += 64) {
#pragma unroll
        for (int rr = 0; rr < 2; ++rr) {
            const int row = srow + rr * 32;
            // A: W1b row (fp32 -> bf16)
            const float* asrc = w1 + (size_t)(i0 + row) * 512 + 256 + k0 + skc;
            const float4 f0 = *(const float4*)(asrc);
            const float4 f1 = *(const float4*)(asrc + 4);
            ushort4 a0, a1;
            a0.x = f2b(f0.x); a0.y = f2b(f0.y); a0.z = f2b(f0.z); a0.w = f2b(f0.w);
            a1.x = f2b(f1.x); a1.y = f2b(f1.y); a1.z = f2b(f1.z); a1.w = f2b(f1.w);
            *(ushort4*)(As + row * 72 + skc)     = a0;
            *(ushort4*)(As + row * 72 + skc + 4) = a1;
            // B: Ws[j][k] = Wm[k, j]  (strided fp32 -> bf16; tiny matrix)
            const float* bsrc = mw + (size_t)(k0 + skc) * 256 + (j0 + row);
            ushort4 b0, b1;
            b0.x = f2b(bsrc[0 * 256]); b0.y = f2b(bsrc[1 * 256]);
            b0.z = f2b(bsrc[2 * 256]); b0.w = f2b(bsrc[3 * 256]);
            b1.x = f2b(bsrc[4 * 256]); b1.y = f2b(bsrc[5 * 256]);
            b1.z = f2b(bsrc[6 * 256]); b1.w = f2b(bsrc[7 * 256]);
            *(ushort4*)(Ws + row * 72 + skc)     = b0;
            *(ushort4*)(Ws + row * 72 + skc + 4) = b1;
        }
        __syncthreads();
#pragma unroll
        for (int kk = 0; kk < 64; kk += 32) {
            const bf16x8 af = *(const bf16x8*)(As + (wid * 16 + ln) * 72 + kk + quad * 8);
#pragma unroll
            for (int f = 0; f < 4; ++f) {
                const bf16x8 wf = *(const bf16x8*)(Ws + (f * 16 + ln) * 72 + kk + quad * 8);
                acc[f] = MFMA16(wf, af, acc[f]);
            }
        }
        __syncthreads();
    }
    const int rowm = i0 + wid * 16 + ln;
#pragma unroll
    for (int f = 0; f < 4; ++f) {
        const int cb = j0 + f * 16 + quad * 4;
        ushort4 ov;
        ov.x = f2b(acc[f][0]); ov.y = f2b(acc[f][1]);
        ov.z = f2b(acc[f][2]); ov.w = f2b(acc[f][3]);
        *(ushort4*)(o + 131072 + (size_t)rowm * 512 + 256 + cb) = ov;
    }
}

// --------------------- fused qk+v projection (64x64 tile) -------------------
// A[8192,256] @ Wqv[512,256]^T. Cols 0-255 -> qkb (scaled, row-major).
// Cols 256-511 -> vtb TRANSPOSED: vtb[feat*8192 + token].
__global__ __launch_bounds__(256) void gemm_qkv(
    const unsigned short* __restrict__ A, const unsigned short* __restrict__ W,
    unsigned short* __restrict__ qkb, unsigned short* __restrict__ vtb)
{
    constexpr int K = 256;
    __shared__ unsigned short As[64 * 72];
    __shared__ unsigned short Ws[64 * 72];
    const int tid  = threadIdx.x;
    const int wid  = tid >> 6;
    const int lane = tid & 63;
    const int ln   = lane & 15;
    const int quad = lane >> 4;
    const int m0 = blockIdx.x * 64, n0 = blockIdx.y * 64;
    f32x4 acc[4] = {{0,0,0,0},{0,0,0,0},{0,0,0,0},{0,0,0,0}};
    const int srow = tid >> 3;          // 0..31 (and +32)
    const int skc  = (tid & 7) * 8;
    const unsigned short* aP0 = A + (size_t)(m0 + srow)      * K + skc;
    const unsigned short* aP1 = A + (size_t)(m0 + srow + 32) * K + skc;
    const unsigned short* wP0 = W + (size_t)(n0 + srow)      * K + skc;
    const unsigned short* wP1 = W + (size_t)(n0 + srow + 32) * K + skc;
    for (int k0 = 0; k0 < K; k0 += 64) {
        *(uint4*)(As + srow * 72 + skc)        = *(const uint4*)(aP0 + k0);
        *(uint4*)(As + (srow + 32) * 72 + skc) = *(const uint4*)(aP1 + k0);
        *(uint4*)(Ws + srow * 72 + skc)        = *(const uint4*)(wP0 + k0);
        *(uint4*)(Ws + (srow + 32) * 72 + skc) = *(const uint4*)(wP1 + k0);
        __syncthreads();
#pragma unroll
        for (int kk = 0; kk < 64; kk += 32) {
            const bf16x8 af = *(const bf16x8*)(As + (wid * 16 + ln) * 72 + kk + quad * 8);
#pragma unroll
            for (int f = 0; f < 4; ++f) {
                const bf16x8 wf = *(const bf16x8*)(Ws + (f * 16 + ln) * 72 + kk + quad * 8);
                acc[f] = MFMA16(wf, af, acc[f]);
            }
        }
        __syncthreads();
    }
    const int rowm = m0 + wid * 16 + ln;
    if (n0 < 256) {   // qk half, scaled, row-major
#pragma unroll
        for (int f = 0; f < 4; ++f) {
            const int cb = n0 + f * 16 + quad * 4;
            ushort4 o;
            o.x = f2b(acc[f][0] * QK_SCALE); o.y = f2b(acc[f][1] * QK_SCALE);
            o.z = f2b(acc[f][2] * QK_SCALE); o.w = f2b(acc[f][3] * QK_SCALE);
            *(ushort4*)(qkb + (size_t)rowm * 256 + cb) = o;
        }
    } else {          // v half, transposed store [feat][token]
#pragma unroll
        for (int f = 0; f < 4; ++f) {
            const int cb = (n0 - 256) + f * 16 + quad * 4;
#pragma unroll
            for (int r = 0; r < 4; ++r)
                vtb[(size_t)(cb + r) * 8192 + rowm] = f2b(acc[f][r]);
        }
    }
}

// ------------------------- 128x128-tile GEMM (fc1/fc2) ----------------------
// 4 waves, each 64x64 (4x4 frags). out = act(A@W^T + bias).
// R12-proven staging: uint4 -> padded-72 LDS.
template <bool GELU_, bool OUTB>
__global__ __launch_bounds__(256) void gemm128(
    const unsigned short* __restrict__ A, const unsigned short* __restrict__ W,
    const float* __restrict__ bias,
    unsigned short* __restrict__ outB, float* __restrict__ outF,
    int K, int NS)   // NS = output row stride
{
    __shared__ unsigned short As[128 * 72];
    __shared__ unsigned short Ws[128 * 72];
    const int tid  = threadIdx.x;
    const int wid  = tid >> 6;
    const int lane = tid & 63;
    const int ln   = lane & 15;
    const int quad = lane >> 4;
    const int m0 = blockIdx.x * 128, n0 = blockIdx.y * 128;
    const int wm = (wid & 1) * 64, wn = (wid >> 1) * 64;
    f32x4 acc[4][4];
#pragma unroll
    for (int f = 0; f < 4; ++f)
#pragma unroll
        for (int i = 0; i < 4; ++i) acc[f][i] = (f32x4){0, 0, 0, 0};
    const int sr = tid >> 2;        // 0..63 (and +64)
    const int sc = (tid & 3) * 8;   // 0..24 (and +32)
    for (int k0 = 0; k0 < K; k0 += 64) {
        const unsigned short* aB = A + (size_t)m0 * K + k0;
        const unsigned short* wB = W + (size_t)n0 * K + k0;
        *(uint4*)(As + sr * 72 + sc)             = *(const uint4*)(aB + (size_t)sr * K + sc);
        *(uint4*)(As + sr * 72 + sc + 32)        = *(const uint4*)(aB + (size_t)sr * K + sc + 32);
        *(uint4*)(As + (sr + 64) * 72 + sc)      = *(const uint4*)(aB + (size_t)(sr + 64) * K + sc);
        *(uint4*)(As + (sr + 64) * 72 + sc + 32) = *(const uint4*)(aB + (size_t)(sr + 64) * K + sc + 32);
        *(uint4*)(Ws + sr * 72 + sc)             = *(const uint4*)(wB + (size_t)sr * K + sc);
        *(uint4*)(Ws + sr * 72 + sc + 32)        = *(const uint4*)(wB + (size_t)sr * K + sc + 32);
        *(uint4*)(Ws + (sr + 64) * 72 + sc)      = *(const uint4*)(wB + (size_t)(sr + 64) * K + sc);
        *(uint4*)(Ws + (sr + 64) * 72 + sc + 32) = *(const uint4*)(wB + (size_t)(sr + 64) * K + sc + 32);
        __syncthreads();
#pragma unroll
        for (int kk = 0; kk < 64; kk += 32) {
            bf16x8 af[4], wf[4];
#pragma unroll
            for (int i = 0; i < 4; ++i)
                af[i] = *(const bf16x8*)(As + (wm + i * 16 + ln) * 72 + kk + quad * 8);
#pragma unroll
            for (int f = 0; f < 4; ++f)
                wf[f] = *(const bf16x8*)(Ws + (wn + f * 16 + ln) * 72 + kk + quad * 8);
#pragma unroll
            for (int f = 0; f < 4; ++f)
#pragma unroll
                for (int i = 0; i < 4; ++i)
                    acc[f][i] = MFMA16(wf[f], af[i], acc[f][i]);
        }
        __syncthreads();
    }
#pragma unroll
    for (int f = 0; f < 4; ++f) {
        const int feat = n0 + wn + f * 16 + quad * 4;
        const float4 b4 = *(const float4*)(bias + feat);
#pragma unroll
        for (int i = 0; i < 4; ++i) {
            const int token = m0 + wm + i * 16 + ln;
            float vv[4] = {acc[f][i][0] + b4.x, acc[f][i][1] + b4.y,
                           acc[f][i][2] + b4.z, acc[f][i][3] + b4.w};
            if (GELU_) {
#pragma unroll
                for (int r = 0; r < 4; ++r) vv[r] = gelu_f(vv[r]);
            }
            if (OUTB) {
                ushort4 o;
                o.x = f2b(vv[0]); o.y = f2b(vv[1]); o.z = f2b(vv[2]); o.w = f2b(vv[3]);
                *(ushort4*)(outB + (size_t)token * NS + feat) = o;
            } else {
                float4 o = {vv[0], vv[1], vv[2], vv[3]};
                *(float4*)(outF + (size_t)token * NS + feat) = o;
            }
        }
    }
}

// ------------------------------- Attention ---------------------------------
// dir 0: m0 = softmax_s(sim) @ v1 ; dir 1: m1 = softmax_l(sim)^T @ v0.
// R6 VERBATIM main loop (measured 42.9 µs); R13 direct-acat store.
__global__ __launch_bounds__(256, 4) void attn_kernel(
    const unsigned short* __restrict__ qk, const unsigned short* __restrict__ vtb,
    unsigned short* __restrict__ mo)   // = acat
{
    __shared__ unsigned short Pw[4][64 * 32];  // per-wave P [64 q][32 keys], swizzled
    const int tid  = threadIdx.x;
    const int wid  = tid >> 6;
    const int lane = tid & 63;
    const int ln   = lane & 15;
    const int quad = lane >> 4;
    const int dir = blockIdx.z, bh = blockIdx.y;
    const int b = bh >> 3, h = bh & 7;
    const int qbase = b * 2048 + (dir ? 4096 : 0);
    const int kbase = b * 2048 + (dir ? 0 : 4096);
    const int q0 = blockIdx.x * 64;
    const int xsw = ((ln >> 1) & 1) << 4;   // xor swizzle, 16-ushort granule

    // Q fragments (B-operand): lane -> q row = ln, d-chunk = quad.
    bf16x8 qf[4];
#pragma unroll
    for (int qg = 0; qg < 4; ++qg)
        qf[qg] = *(const bf16x8*)(qk + (size_t)(qbase + q0 + qg * 16 + ln) * 256 + h * 32 + quad * 8);

    f32x4 oacc[4][2];
#pragma unroll
    for (int qg = 0; qg < 4; ++qg) {
        oacc[qg][0] = (f32x4){0, 0, 0, 0};
        oacc[qg][1] = (f32x4){0, 0, 0, 0};
    }
    float lp[4] = {0.0f, 0.0f, 0.0f, 0.0f};
    const f32x4 zf = {0, 0, 0, 0};

    // this wave's key slice: keys kbase + it*128 + wid*32 + [0..32)
    const unsigned short* kp = qk  + (size_t)(kbase + wid * 32 + ln) * 256 + h * 32 + quad * 8;
    const unsigned short* vp = vtb + (size_t)(h * 32 + ln) * 8192 + (kbase + wid * 32) + quad * 8;

    unsigned short* Pq[4];
#pragma unroll
    for (int qg = 0; qg < 4; ++qg) Pq[qg] = &Pw[wid][(qg * 16 + ln) * 32];

    bf16x8 kc0 = *(const bf16x8*)(kp);
    bf16x8 kc1 = *(const bf16x8*)(kp + 16 * 256);
    bf16x8 vc0 = *(const bf16x8*)(vp);
    bf16x8 vc1 = *(const bf16x8*)(vp + 16 * 8192);
    bf16x8 kn0, kn1, vn0, vn1;

    for (int it = 0; it < 16; ++it) {
        // S^T = K @ Q^T for the 32-key slice (C: row=key, col=q) -> exp -> P
#pragma unroll
        for (int sub = 0; sub < 2; ++sub) {
            const bf16x8 kf = sub ? kc1 : kc0;
            f32x4 s[4];
#pragma unroll
            for (int qg = 0; qg < 4; ++qg) s[qg] = MFMA16(kf, qf[qg], zf);
#pragma unroll
            for (int qg = 0; qg < 4; ++qg) {
                const float e0 = exp2_fast(s[qg][0]), e1 = exp2_fast(s[qg][1]);
                const float e2 = exp2_fast(s[qg][2]), e3 = exp2_fast(s[qg][3]);
                lp[qg] += (e0 + e1) + (e2 + e3);
                ushort4 pb;
                pb.x = f2b(e0); pb.y = f2b(e1); pb.z = f2b(e2); pb.w = f2b(e3);
                // P[q][key = sub*16 + quad*4 + r], chunk xor-swizzled
                *(ushort4*)(Pq[qg] + ((sub * 16 + quad * 4) ^ xsw)) = pb;
            }
        }
        // prefetch next key slice (global; vmcnt-tracked, unaffected by lgkm fence)
        if (it < 15) {
            const unsigned short* kpn = kp + (size_t)(it + 1) * 128 * 256;
            const unsigned short* vpn = vp + (it + 1) * 128;
            kn0 = *(const bf16x8*)(kpn);
            kn1 = *(const bf16x8*)(kpn + 16 * 256);
            vn0 = *(const bf16x8*)(vpn);
            vn1 = *(const bf16x8*)(vpn + 16 * 8192);
        }
        // P is wave-private: drain own ds_writes before reading (no barrier)
        asm volatile("s_waitcnt lgkmcnt(0)" ::: "memory");
        // O^T += V^T @ P  (k = 32 keys, exactly this wave's slice)
#pragma unroll
        for (int qg = 0; qg < 4; ++qg) {
            const bf16x8 pf = *(const bf16x8*)(Pq[qg] + ((quad * 8) ^ xsw));
            oacc[qg][0] = MFMA16(vc0, pf, oacc[qg][0]);
            oacc[qg][1] = MFMA16(vc1, pf, oacc[qg][1]);
        }
        if (it < 15) { kc0 = kn0; kc1 = kn1; vc0 = vn0; vc1 = vn1; }
    }

    // ---- cross-wave reduction (each wave holds partials over 512 keys) ----
#pragma unroll
    for (int qg = 0; qg < 4; ++qg) {   // sum over quads -> full wave-slice sum
        lp[qg] += __shfl_xor(lp[qg], 16);
        lp[qg] += __shfl_xor(lp[qg], 32);
    }
    __syncthreads();                   // all waves done with their Pw
    float* scr  = (float*)&Pw[0][0];
    float* Lbuf = scr;                 // [4 wid][64 q]
    float* Obuf = scr + 256;           // [4 wid][2 dg][64 lane][4]
    if (quad == 0) {
#pragma unroll
        for (int qg = 0; qg < 4; ++qg) Lbuf[wid * 64 + qg * 16 + ln] = lp[qg];
    }
#pragma unroll
    for (int qg = 0; qg < 4; ++qg) {
#pragma unroll
        for (int dg = 0; dg < 2; ++dg)
            *(f32x4*)&Obuf[(wid * 2 + dg) * 256 + lane * 4] = oacc[qg][dg];
        __syncthreads();
        if (wid == qg) {
            const int q = qg * 16 + ln;
            const float rinv = 1.0f /
                (Lbuf[q] + Lbuf[64 + q] + Lbuf[128 + q] + Lbuf[192 + q]);
            // write straight into acat[:, 256:512]  (row stride 512)
            const size_t orow = (size_t)(qbase + q0 + q) * 512 + 256 + h * 32;
#pragma unroll
            for (int dg = 0; dg < 2; ++dg) {
                f32x4 sum = *(f32x4*)&Obuf[(0 + dg) * 256 + lane * 4];
#pragma unroll
                for (int w = 1; w < 4; ++w)
                    sum += *(f32x4*)&Obuf[(w * 2 + dg) * 256 + lane * 4];
                ushort4 o;
                o.x = f2b(sum[0] * rinv); o.y = f2b(sum[1] * rinv);
                o.z = f2b(sum[2] * rinv); o.w = f2b(sum[3] * rinv);
                *(ushort4*)(mo + orow + dg * 16 + quad * 4) = o;
            }
        }
        __syncthreads();
    }
}

// ------------------------ residual + gamma * LN2(h) -------------------------
__global__ __launch_bounds__(256) void ln_out_kernel(
    const float* __restrict__ x0, const float* __restrict__ x1,
    const float* __restrict__ h2, const float* __restrict__ w,
    const float* __restrict__ b,  const float* __restrict__ gamma,
    float* __restrict__ out)
{
    const int wid  = threadIdx.x >> 6;
    const int lane = threadIdx.x & 63;
    const int row  = blockIdx.x * 4 + wid;
    const int c0 = lane * 4;
    const float4 hv = *(const float4*)(h2 + (size_t)row * 256 + c0);
    float s  = (hv.x + hv.y) + (hv.z + hv.w);
    float sq = (hv.x * hv.x + hv.y * hv.y) + (hv.z * hv.z + hv.w * hv.w);
#pragma unroll
    for (int off = 1; off < 64; off <<= 1) {
        s  += __shfl_xor(s,  off);
        sq += __shfl_xor(sq, off);
    }
    const float mean = s * (1.0f / 256.0f);
    const float var  = sq * (1.0f / 256.0f) - mean * mean;
    const float rs   = rsqrtf(var + 1e-5f);
    const float* xr = (row < 4096) ? (x0 + (size_t)row * 256)
                                   : (x1 + (size_t)(row - 4096) * 256);
    const float4 xv = *(const float4*)(xr + c0);
    const float4 w4 = *(const float4*)(w + c0);
    const float4 b4 = *(const float4*)(b + c0);
    const float4 g4 = *(const float4*)(gamma + c0);
    float4 y;
    y.x = xv.x + g4.x * ((hv.x - mean) * rs * w4.x + b4.x);
    y.y = xv.y + g4.y * ((hv.y - mean) * rs * w4.y + b4.y);
    y.z = xv.z + g4.z * ((hv.z - mean) * rs * w4.z + b4.z);
    y.w = xv.w + g4.w * ((hv.w - mean) * rs * w4.w + b4.w);
    *(float4*)(out + (size_t)row * 256 + c0) = y;
}

// ---------------------------------------------------------------------------
extern "C" void kernel_launch(void* const* d_in, const int* in_sizes, int n_in,
                              void* d_out, int out_size, void* d_ws, size_t ws_size,
                              hipStream_t stream) {
    (void)in_sizes; (void)n_in; (void)out_size; (void)ws_size;
    const float* x0      = (const float*)d_in[0];
    const float* x1      = (const float*)d_in[1];
    const float* qk_w    = (const float*)d_in[2];
    const float* v_w     = (const float*)d_in[3];
    const float* merge_w = (const float*)d_in[4];
    const float* ln1_w   = (const float*)d_in[5];
    const float* ln1_b   = (const float*)d_in[6];
    const float* ln2_w   = (const float*)d_in[7];
    const float* ln2_b   = (const float*)d_in[8];
    const float* fc1_w   = (const float*)d_in[9];
    const float* fc1_b   = (const float*)d_in[10];
    const float* fc2_w   = (const float*)d_in[11];
    const float* fc2_b   = (const float*)d_in[12];
    const float* gamma   = (const float*)d_in[13];
    float* out = (float*)d_out;

    unsigned short* nb   = (unsigned short*)d_ws;            // [8192,256] LN1 out
    unsigned short* qkb  = nb   + (size_t)ROWS * 256;        // [8192,256] qk proj (scaled)
    unsigned short* vtb  = qkb  + (size_t)ROWS * 256;        // [256,8192] v proj TRANSPOSED
    unsigned short* acat = vtb  + (size_t)ROWS * 256;        // [8192,512] concat(x, attn)
    unsigned short* fc1o = acat + (size_t)ROWS * 512;        // [8192,1024] gelu(fc1)
    float*          h2   = (float*)(fc1o + (size_t)ROWS * 1024);  // [8192,256] fc2 out
    unsigned short* wqv  = (unsigned short*)(h2 + (size_t)ROWS * 256);  // [512,256]
    unsigned short* w1f  = wqv + 131072;                     // [1024,512] fused fc1 W
    unsigned short* w2b  = w1f + 524288;                     // [256,1024]

    prep_kernel<<<4672, 256, 0, stream>>>(
        qk_w, v_w, merge_w, fc1_w, fc2_w, wqv,
        x0, x1, ln1_w, ln1_b, nb, acat);

    gemm_qkv<<<dim3(128, 8), 256, 0, stream>>>(nb, wqv, qkb, vtb);

    attn_kernel<<<dim3(32, 16, 2), 256, 0, stream>>>(qkb, vtb, acat);

    gemm128<true, true><<<dim3(64, 8), 256, 0, stream>>>(
        acat, w1f, fc1_b, fc1o, nullptr, 512, 1024);
    gemm128<false, false><<<dim3(64, 2), 256, 0, stream>>>(
        fc1o, w2b, fc2_b, nullptr, h2, 1024, 256);

    ln_out_kernel<<<2048, 256, 0, stream>>>(x0, x1, h2, ln2_w, ln2_b, gamma, out);
}